// Round 4
// baseline (10516.656 us; speedup 1.0000x reference)
//
#include <hip/hip_runtime.h>
#include <cstdint>
#include <cstddef>

typedef _Float16 f16;
typedef __attribute__((ext_vector_type(2))) _Float16 f16x2;
typedef __attribute__((ext_vector_type(8))) _Float16 f16x8;
typedef __attribute__((ext_vector_type(4))) float f32x4;

static constexpr int Tq = 128, BT = 8192;
static constexpr float SCA = 256.f;        // operand pre-scale (avoids fp16 subnormals)
static constexpr float SLO = 2048.f;       // lo-part scale (2^11)
static constexpr float INV_LO = 4.8828125e-4f;      // 1/2048
static constexpr float INV_SC = 1.52587890625e-5f;  // 1/65536

__device__ inline void split256(float x, f16& hi, f16& lo) {
  float xs = x * SCA;
  hi = (f16)xs;
  lo = (f16)((xs - (float)hi) * SLO);
}

// ---------------- weight packing ----------------
// Fragment layout: chunk[lane][e] = M[k = kk*32 + (lane>>4)*8 + e][col = n0*16 + (lane&15)]
// B global layout per j: [n0][kk][2(hi,lo)][512]
__global__ __launch_bounds__(256) void pack_l2s(const float* __restrict__ l2sW,
                                                f16* __restrict__ bp)
{
  int id = blockIdx.x * 256 + threadIdx.x;   // 131072 = 2048 u * 64
  int lane = id & 63; int u = id >> 6;       // u = n0*64 + kk
  int kk = u & 63, n0 = u >> 6;
  int k = kk * 32 + ((lane >> 4) * 8), n = n0 * 16 + (lane & 15);
  const float* s = l2sW + (long)k * 512 + n;
  f16x8 vh, vl;
#pragma unroll
  for (int e = 0; e < 8; e++) { f16 hi, lo; split256(s[(long)e * 512], hi, lo); vh[e] = hi; vl[e] = lo; }
  long base = ((long)u * 2) * 512 + lane * 8;
  *(f16x8*)&bp[base] = vh;
  *(f16x8*)&bp[base + 512] = vl;
}

__global__ __launch_bounds__(256) void pack_layer(
    const float* __restrict__ Wx, const float* __restrict__ Wh,
    const float* __restrict__ Wc, f16* __restrict__ bprexL,
    f16* __restrict__ bscxL, f16* __restrict__ wrecL, int l)
{
  long id = (long)blockIdx.x * 256 + threadIdx.x;  // 2,621,440
  int lane = id & 63; long u = id >> 6;
  if (u < 20480) {  // bprex: u = (j*640 + n0)*16 + kk ; cols: X|k1|k3s|k4s
    int kk = u & 15; long v = u >> 4; int n0 = (int)(v % 640); int j = (int)(v / 640);
    int c = n0 * 16 + (lane & 15); int slot = c / 2560, f = c % 2560;
    int k = kk * 32 + ((lane >> 4) * 8);
    int lj = l * 2 + j, ljo = l * 2 + (1 - j);
    const float* s;
    if (slot == 0)      s = Wx + ((long)lj * 512 + k) * 2560 + f;
    else if (slot == 1) s = Wc + (((long)lj * 6 + 1) * 512 + k) * 2560 + f;
    else if (slot == 2) s = Wc + (((long)ljo * 6 + 3) * 512 + k) * 2560 + f;
    else                s = Wc + (((long)ljo * 6 + 4) * 512 + k) * 2560 + f;
    f16x8 vh, vl;
#pragma unroll
    for (int e = 0; e < 8; e++) { f16 hi, lo; split256(s[(long)e * 2560], hi, lo); vh[e] = hi; vl[e] = lo; }
    long base = (u * 2) * 512 + lane * 8;
    *(f16x8*)&bprexL[base] = vh; *(f16x8*)&bprexL[base + 512] = vl;
    return;
  }
  u -= 20480;
  if (u < 5120) {  // bscx: u = (j*160 + n0)*16 + kk ; src cW[l][j][5]
    int kk = u & 15; long v = u >> 4; int n0 = (int)(v % 160); int j = (int)(v / 160);
    int f = n0 * 16 + (lane & 15);
    int k = kk * 32 + ((lane >> 4) * 8);
    const float* s = Wc + (((long)(l * 2 + j) * 6 + 5) * 512 + k) * 2560 + f;
    f16x8 vh, vl;
#pragma unroll
    for (int e = 0; e < 8; e++) { f16 hi, lo; split256(s[(long)e * 2560], hi, lo); vh[e] = hi; vl[e] = lo; }
    long base = (u * 2) * 512 + lane * 8;
    *(f16x8*)&bscxL[base] = vh; *(f16x8*)&bscxL[base + 512] = vl;
    return;
  }
  u -= 5120;
  {  // wrec: u = ((j*5+g)*32+ht)*48+kk ; K = [hW | cW0 | cW2]
    int kk = (int)(u % 48); long v = u / 48; int ht = (int)(v & 31); v >>= 5;
    int g = (int)(v % 5); int j = (int)(v / 5);
    int f = g * 512 + ht * 16 + (lane & 15);
    int k = kk * 32 + ((lane >> 4) * 8);
    int seg = k >> 9, k5 = k & 511;
    int lj = l * 2 + j;
    const float* s;
    if (seg == 0)      s = Wh + ((long)lj * 512 + k5) * 2560 + f;
    else if (seg == 1) s = Wc + (((long)lj * 6 + 0) * 512 + k5) * 2560 + f;
    else               s = Wc + (((long)lj * 6 + 2) * 512 + k5) * 2560 + f;
    f16x8 vh, vl;
#pragma unroll
    for (int e = 0; e < 8; e++) { f16 hi, lo; split256(s[(long)e * 2560], hi, lo); vh[e] = hi; vl[e] = lo; }
    long base = (u * 2) * 512 + lane * 8;
    *(f16x8*)&wrecL[base] = vh; *(f16x8*)&wrecL[base + 512] = vl;
  }
}

// ---------------- scene f32[b,t] -> f32[t,b] transpose copy ----------------
__global__ __launch_bounds__(256) void cpy_scene(const float* __restrict__ src,
                                                 float* __restrict__ dst)
{
  int row = blockIdx.x;          // b*128 + t
  int b = row >> 7, t = row & 127;
  long so = (long)row * 512, dofs = ((long)(t * 64 + b)) * 512;
  for (int d = threadIdx.x; d < 512; d += 256) dst[dofs + d] = src[so + d];
}

// ---------------- group separation (f32, t-major seqin) ----------------
__global__ __launch_bounds__(64) void groupsep(const float* __restrict__ feat,
    const float* __restrict__ sepW, const float* __restrict__ sepb,
    float* __restrict__ seqin)
{
  const int row = blockIdx.x;    // b*128+t
  const int b = row >> 7, t = row & 127;
  const int lane = threadIdx.x;
  const float* fb = feat + (long)row * 2048;
  const int d0 = lane * 8;
  float x[4][8];
  float part[4] = {0.f, 0.f, 0.f, 0.f};
  float wv[8];
#pragma unroll
  for (int e = 0; e < 8; e++) wv[e] = sepW[d0 + e];
#pragma unroll
  for (int m = 0; m < 4; m++) {
    const float4* p4 = (const float4*)(fb + m * 512 + d0);
    float4 u0 = p4[0], u1 = p4[1];
    x[m][0]=u0.x; x[m][1]=u0.y; x[m][2]=u0.z; x[m][3]=u0.w;
    x[m][4]=u1.x; x[m][5]=u1.y; x[m][6]=u1.z; x[m][7]=u1.w;
#pragma unroll
    for (int e = 0; e < 8; e++) part[m] += x[m][e] * wv[e];
  }
#pragma unroll
  for (int o = 32; o; o >>= 1) {
#pragma unroll
    for (int m = 0; m < 4; m++) part[m] += __shfl_xor(part[m], o);
  }
  float bias = sepb[0];
  float lg[4]; float mx = -1e30f;
#pragma unroll
  for (int m = 0; m < 4; m++) { lg[m] = part[m] + bias; mx = fmaxf(mx, lg[m]); }
  float ex[4]; float sum = 0.f;
#pragma unroll
  for (int m = 0; m < 4; m++) { ex[m] = expf(lg[m] - mx); sum += ex[m]; }
  float sw[4]; float c0 = 0.f;
#pragma unroll
  for (int m = 0; m < 4; m++) { sw[m] = (ex[m] / sum - 0.25f) > 0.f ? 1.f : 0.f; c0 += sw[m]; }
  float inv0 = 1.f / (c0 + 1e-8f), inv1 = 1.f / ((4.f - c0) + 1e-8f);
  long dofs = ((long)(t * 64 + b)) * 512 + d0;
#pragma unroll
  for (int e = 0; e < 8; e++) {
    float a0 = 0.f, a1 = 0.f;
#pragma unroll
    for (int m = 0; m < 4; m++) { a0 += sw[m] * x[m][e]; a1 += (1.f - sw[m]) * x[m][e]; }
    seqin[dofs + e] = a0 * inv0;
    seqin[(long)BT * 512 + dofs + e] = a1 * inv1;
  }
}

// ---------------- 128x64 tiled split-fp16 GEMM (f32-faithful) ----------------
// A f32 row-major (+z stride), B pre-split-packed, C f32.
template<bool RELU>
__global__ __launch_bounds__(256) void gemm_split(
    const float* __restrict__ Ap, long sAz, const f16* __restrict__ Bp, long sBz,
    float* __restrict__ Cp, long sCz, const float* __restrict__ bias,
    int Kd, long ldc)
{
  __shared__ f16 AhS[8 * 64 * 8], AlS[8 * 64 * 8];
  __shared__ f16 BhS[4 * 64 * 8], BlS[4 * 64 * 8];
  const int tid = threadIdx.x, lane = tid & 63, w = tid >> 6;
  const int mt = blockIdx.y, nt = blockIdx.x, z = blockIdx.z;
  const int mgroup = w & 1, ngroup = w >> 1;
  const float* Az = Ap + sAz * z;
  const f16* Bz = Bp + sBz * z;
  f32x4 acc1[4][2], acc2[4][2];
#pragma unroll
  for (int i = 0; i < 4; i++)
#pragma unroll
    for (int jn = 0; jn < 2; jn++) { acc1[i][jn] = (f32x4)(0.f); acc2[i][jn] = (f32x4)(0.f); }
  const int kt = Kd >> 5;
  for (int kk = 0; kk < kt; ++kk) {
    __syncthreads();
    // stage A (split from f32)
    for (int c = tid; c < 512; c += 256) {
      int r = c >> 2, q = c & 3;
      const float* s = Az + ((long)mt * 128 + r) * Kd + kk * 32 + q * 8;
      f16x8 vh, vl;
#pragma unroll
      for (int e = 0; e < 8; e++) { f16 hi, lo; split256(s[e], hi, lo); vh[e] = hi; vl[e] = lo; }
      int li = (((r >> 4) * 64) + ((r & 15) + 16 * q)) * 8;
      *(f16x8*)&AhS[li] = vh;
      *(f16x8*)&AlS[li] = vl;
    }
    // stage B (pre-split in global)
#pragma unroll
    for (int r2 = 0; r2 < 2; ++r2) {
      int idx = w * 2 + r2; int s = idx >> 1, hh = idx & 1;
      f16x8 v = *(const f16x8*)&Bz[(((long)(nt * 4 + s) * kt + kk) * 2 + hh) * 512 + lane * 8];
      f16* dst = hh ? BlS : BhS;
      *(f16x8*)&dst[(s * 64 + lane) * 8] = v;
    }
    __syncthreads();
    f16x8 ah[4], al[4], bh[2], bl[2];
#pragma unroll
    for (int i = 0; i < 4; i++) {
      int m16 = mgroup * 4 + i;
      ah[i] = *(f16x8*)&AhS[(m16 * 64 + lane) * 8];
      al[i] = *(f16x8*)&AlS[(m16 * 64 + lane) * 8];
    }
#pragma unroll
    for (int jn = 0; jn < 2; jn++) {
      int n16 = ngroup * 2 + jn;
      bh[jn] = *(f16x8*)&BhS[(n16 * 64 + lane) * 8];
      bl[jn] = *(f16x8*)&BlS[(n16 * 64 + lane) * 8];
    }
#pragma unroll
    for (int i = 0; i < 4; i++)
#pragma unroll
      for (int jn = 0; jn < 2; jn++) {
        acc1[i][jn] = __builtin_amdgcn_mfma_f32_16x16x32_f16(ah[i], bh[jn], acc1[i][jn], 0, 0, 0);
        acc2[i][jn] = __builtin_amdgcn_mfma_f32_16x16x32_f16(ah[i], bl[jn], acc2[i][jn], 0, 0, 0);
        acc2[i][jn] = __builtin_amdgcn_mfma_f32_16x16x32_f16(al[i], bh[jn], acc2[i][jn], 0, 0, 0);
      }
  }
  const int rb = (lane >> 4) * 4, cb_ = lane & 15;
#pragma unroll
  for (int i = 0; i < 4; i++)
#pragma unroll
    for (int jn = 0; jn < 2; jn++) {
      long col = (long)nt * 64 + (ngroup * 2 + jn) * 16 + cb_;
#pragma unroll
      for (int rr = 0; rr < 4; rr++) {
        long row = (long)mt * 128 + (mgroup * 4 + i) * 16 + rb + rr;
        float vv = (acc1[i][jn][rr] + acc2[i][jn][rr] * INV_LO) * INV_SC;
        if constexpr (RELU) {
          vv += bias[col];
          Cp[row * ldc + col] = fmaxf(vv, 0.f);
        } else {
          (Cp + sCz * z)[row * ldc + col] = vv;
        }
      }
    }
}

// ---------------- fused recurrent step (split-fp16 recurrent GEMM) ----------------
// grid 256 = (btile<<6) | (j<<5) | ht  (bid%8 = ht%8 -> XCD-pinned wrec slices)
__global__ __launch_bounds__(320) void step_kernel(
    const f16* __restrict__ wrecL, const float* __restrict__ ring,
    unsigned int* __restrict__ hsplit, float* __restrict__ lbuf,
    float* __restrict__ sgbuf, float* __restrict__ cellg,
    float* __restrict__ shstat, const float* __restrict__ sharef,
    float* __restrict__ shout, float* __restrict__ seqin,
    float* __restrict__ out,
    const float* __restrict__ archW, const float* __restrict__ archB,
    const float* __restrict__ bx, const float* __restrict__ bh,
    const float* __restrict__ cbias, int l, int t, int logch)
{
  __shared__ float wls[16][8];
  __shared__ f16 AhiS[2][16][264];   // 256 + 8 pad
  __shared__ f16 AloS[2][16][264];
  __shared__ float G[5][16][17];
  __shared__ float HnS[16][17];
  const int tid = threadIdx.x;
  const int wg = blockIdx.x;
  const int ht = wg & 31, j = (wg >> 5) & 1, btile = wg >> 6;
  const int lj = l * 2 + j;
  const int CHm1 = (1 << logch) - 1;
  const long chrows = 64L << logch;

  // phase 1: top-2 gating weights
  if (tid < 16) {
    int b = btile * 16 + tid;
    const float* lb = lbuf + ((long)t * 2 + j) * 64 * 8 + b * 8;
    float lg[6];
#pragma unroll
    for (int k = 0; k < 6; k++) lg[k] = lb[k] + archB[l * 6 + k];
    int k1 = 0; float v1 = lg[0];
#pragma unroll
    for (int k = 1; k < 6; k++) if (lg[k] > v1) { v1 = lg[k]; k1 = k; }
    int k2 = -1; float v2 = -1e30f;
#pragma unroll
    for (int k = 0; k < 6; k++) if (k != k1 && lg[k] > v2) { v2 = lg[k]; k2 = k; }
#pragma unroll
    for (int k = 0; k < 6; k++) wls[tid][k] = (k == k1 || k == k2) ? 0.5f : 0.f;
  }
  // phase 2: delayed share update for step t-1 (j==0 blocks)
  if (j == 0 && t > 0 && tid < 256) {
    int r = tid >> 4, hh_ = tid & 15;
    int b = btile * 16 + r, h = ht * 16 + hh_;
    int p = (t - 1) & 1;
    long ibh = (long)b * 512 + h;
    float sg = sgbuf[(long)(p * 2 + 0) * 32768 + ibh] + sgbuf[(long)(p * 2 + 1) * 32768 + ibh];
    float gate = 1.f / (1.f + expf(-sg));
    long rowp = (long)b * Tq + (t - 1);
    float shf = ((l == 0) ? sharef : shout)[rowp * 512 + h];
    float ss = shstat[ibh] + gate * shf;
    float cm = shstat[32768 + ibh] + gate;
    shstat[ibh] = ss; shstat[32768 + ibh] = cm;
    float sv = ss / cm;
    if (l == 0) shout[rowp * 512 + h] = sv;
    long oidx = rowp * 1536 + 1024 + h;
    if (l == 0) out[oidx] = 0.5f * sv; else out[oidx] += 0.5f * sv;
  }
  __syncthreads();

  // phases 3+4: A staging (pre-split h, exact {0,0.5,1} scaling) + 3-chain MFMA
  auto stageA = [&](int kb, int buf) {
    int seg = kb >> 1;
    int slot = (seg == 1) ? (t & 3) : ((t + 1) & 3);
    int jj = (seg == 2) ? (1 - j) : j;
    const unsigned int* sp = hsplit + ((long)slot * 2 + jj) * 32768;
    int koff0 = (kb & 1) * 256;
    for (int c = tid; c < 2048; c += 320) {
      int r = c >> 7, kp = c & 127;
      int b = btile * 16 + r;
      uint2 v = *(const uint2*)(sp + (long)b * 512 + koff0 + kp * 2);
      float scf = (seg == 0) ? 1.f : wls[r][seg == 1 ? 0 : 2];
      f16 sh = (f16)scf;
      f16x2 a0 = __builtin_bit_cast(f16x2, v.x);
      f16x2 a1 = __builtin_bit_cast(f16x2, v.y);
      f16x2 sv2; sv2[0] = sh; sv2[1] = sh;
      a0 *= sv2; a1 *= sv2;
      f16x2 hp, lp;
      hp[0] = a0[0]; hp[1] = a1[0];
      lp[0] = a0[1]; lp[1] = a1[1];
      *(f16x2*)&AhiS[buf][r][kp * 2] = hp;
      *(f16x2*)&AloS[buf][r][kp * 2] = lp;
    }
  };

  const int wv = tid >> 6, lane = tid & 63;
  f32x4 acc1 = (f32x4)(0.f), acc2 = (f32x4)(0.f);
  const f16* wb = wrecL + (((((long)j * 5 + wv) * 32 + ht) * 48) * 2) * 512 + (long)lane * 8;

  stageA(0, 0);
  for (int kb = 0; kb < 6; ++kb) {
    __syncthreads();
    if (kb < 5) stageA(kb + 1, (kb + 1) & 1);
    int buf = kb & 1;
    const f16* arh = &AhiS[buf][lane & 15][(lane >> 4) * 8];
    const f16* arl = &AloS[buf][lane & 15][(lane >> 4) * 8];
#pragma unroll
    for (int k8 = 0; k8 < 8; ++k8) {
      f16x8 ah = *(const f16x8*)(arh + k8 * 32);
      f16x8 al = *(const f16x8*)(arl + k8 * 32);
      long wo = ((long)(kb * 8 + k8) * 2) * 512;
      f16x8 wh = *(const f16x8*)(wb + wo);
      f16x8 wl = *(const f16x8*)(wb + wo + 512);
      acc1 = __builtin_amdgcn_mfma_f32_16x16x32_f16(ah, wh, acc1, 0, 0, 0);
      acc2 = __builtin_amdgcn_mfma_f32_16x16x32_f16(ah, wl, acc2, 0, 0, 0);
      acc2 = __builtin_amdgcn_mfma_f32_16x16x32_f16(al, wh, acc2, 0, 0, 0);
    }
  }
  {
    int rb = (lane >> 4) * 4, cb_ = lane & 15;
#pragma unroll
    for (int rr = 0; rr < 4; rr++)
      G[wv][rb + rr][cb_] = (acc1[rr] + acc2[rr] * INV_LO) * INV_SC;
  }
  __syncthreads();

  // phase 5: LSTM pointwise + outputs (all f32)
  if (tid < 256) {
    int r = tid >> 4, hh_ = tid & 15;
    int b = btile * 16 + r, h = ht * 16 + hh_;
    long row = (long)b * Tq + t;
    auto xprow = [&](int jj, int ts) -> const float* {
      long slot = (ts >> logch) & 1;
      long rr = (long)(ts & CHm1) * 64 + b;
      return ring + ((slot * 2 + jj) * chrows + rr) * 12800;
    };
    const float* xj = xprow(j, t);
    const float* xo = xprow(1 - j, t);
    float wk[6];
#pragma unroll
    for (int k = 0; k < 6; k++) wk[k] = wls[r][k];
    const bool has_n = (t < Tq - 1);
    const float* xj1 = has_n ? xprow(j, t + 1) : xj;
    const float* xo1 = has_n ? xprow(1 - j, t + 1) : xo;
    float tg[5];
#pragma unroll
    for (int g = 0; g < 5; ++g) {
      int f = g * 512 + h;
      float v = G[g][r][hh_];
      v += xj[f];                                    // seq_t @ xW
      v += bx[(long)lj * 2560 + f] + bh[(long)lj * 2560 + f];
      if (has_n) v += wk[1] * xj1[2560 + f] + wk[4] * xo1[3 * 2560 + f];
      v += wk[3] * xo[2 * 2560 + f];
      v += wk[5] * xj[4 * 2560 + f];
      float cbs = 0.f;
#pragma unroll
      for (int k = 0; k < 6; k++) cbs += wk[k] * cbias[((long)lj * 6 + k) * 2560 + f];
      tg[g] = v + cbs;
    }
    auto sigm = [](float x) { return 1.f / (1.f + expf(-x)); };
    long ijbh = ((long)j * 64 + b) * 512 + h;
    float cell = cellg[ijbh];
    cell = (1.f - sigm(tg[1])) * cell + sigm(tg[0]) * tanhf(tg[4]);
    cellg[ijbh] = cell;
    float hn = sigm(tg[2]) * tanhf(cell);
    // write pre-split h (scaled by 256) for future steps
    {
      float hs = hn * SCA;
      f16 phi = (f16)hs;
      f16 plo = (f16)((hs - (float)phi) * SLO);
      f16x2 pk; pk[0] = phi; pk[1] = plo;
      hsplit[((long)((t + 2) & 3) * 2 + j) * 32768 + (long)b * 512 + h] =
          __builtin_bit_cast(unsigned int, pk);
    }
    if (l == 0) seqin[(long)j * BT * 512 + ((long)t * 64 + b) * 512 + h] = hn;
    long oidx = row * 1536 + (long)j * 512 + h;
    if (l == 0) out[oidx] = 0.5f * hn; else out[oidx] += 0.5f * hn;
    sgbuf[((long)(t & 1) * 2 + j) * 32768 + (long)b * 512 + h] = tg[3];
    HnS[r][hh_] = hn;
  }
  __syncthreads();

  // phase 6: partial logits for step t+1
  if (tid < 96) {
    int r = tid / 6, k = tid % 6;
    int b = btile * 16 + r;
    float s = 0.f;
#pragma unroll
    for (int q = 0; q < 16; q++)
      s += HnS[r][q] * archW[(long)l * 512 * 6 + (ht * 16 + q) * 6 + k];
    atomicAdd(&lbuf[(((long)(t + 1) * 2 + j) * 64 + b) * 8 + k], s);
  }
}

// ---------------- final share step (t = 127) ----------------
__global__ __launch_bounds__(256) void share_fin(
    const float* __restrict__ sgbuf, const float* __restrict__ shstat,
    const float* __restrict__ sharef, float* __restrict__ shout,
    float* __restrict__ out, int l)
{
  int idx = blockIdx.x * 256 + threadIdx.x;
  if (idx >= 32768) return;
  int b = idx >> 9, h = idx & 511;
  const int t = Tq - 1; const int p = t & 1;
  float sg = sgbuf[(long)(p * 2 + 0) * 32768 + idx] + sgbuf[(long)(p * 2 + 1) * 32768 + idx];
  float gate = 1.f / (1.f + expf(-sg));
  long rowp = (long)b * Tq + t;
  float shf = ((l == 0) ? sharef : shout)[rowp * 512 + h];
  float ss = shstat[idx] + gate * shf;
  float cm = shstat[32768 + idx] + gate;
  float sv = ss / cm;
  if (l == 0) shout[rowp * 512 + h] = sv;
  long oidx = rowp * 1536 + 1024 + h;
  if (l == 0) out[oidx] = 0.5f * sv; else out[oidx] += 0.5f * sv;
}

// ---------------- host launcher ----------------
extern "C" void kernel_launch(void* const* d_in, const int* in_sizes, int n_in,
                              void* d_out, int out_size, void* d_ws, size_t ws_size,
                              hipStream_t stream)
{
  const float* feat    = (const float*)d_in[0];
  const float* context = (const float*)d_in[1];
  const float* l2sW    = (const float*)d_in[2];
  const float* l2sb    = (const float*)d_in[3];
  const float* sepW    = (const float*)d_in[4];
  const float* sepb    = (const float*)d_in[5];
  const float* archW   = (const float*)d_in[6];
  const float* archB   = (const float*)d_in[7];
  const float* Wx      = (const float*)d_in[8];
  const float* bx      = (const float*)d_in[9];
  const float* Wh      = (const float*)d_in[10];
  const float* bh      = (const float*)d_in[11];
  const float* Wc      = (const float*)d_in[12];
  const float* cb      = (const float*)d_in[13];
  float* out = (float*)d_out;

  char* w = (char*)d_ws;
  size_t off = 0;
  auto take = [&](size_t b) { size_t o = off; off += b; return o; };
  float* sceneb = (float*)(w + take(16777216));        // f32 [t*64+b][512]
  float* seqin  = (float*)(w + take(33554432));        // f32 [2][t*64+b][512]
  float* sharef = (float*)(w + take(16777216));        // f32 [b*128+t][512]
  float* shout  = (float*)(w + take(16777216));
  f16*   bpl2s  = (f16*)(w + take(4194304));
  f16*   bprexL = (f16*)(w + take(41943040));          // per-layer, repacked
  f16*   bscxL  = (f16*)(w + take(10485760));
  f16*   wrecL  = (f16*)(w + take(31457280));
  unsigned int* hsplit = (unsigned int*)(w + take(1048576));  // [4][2][64][512] (hi,lo)
  float* lbuf   = (float*)(w + take(528384));
  float* sgbuf  = (float*)(w + take(524288));
  float* cellg  = (float*)(w + take(262144));
  float* shstat = (float*)(w + take(262144));
  // adaptive projection ring: f32 [2 slot][2 j][CH*64][12800]
  int logch = 3;
  auto ring_bytes = [](int lc) { return (size_t)(64 << lc) * 204800; };
  while (logch > 1 && off + ring_bytes(logch) > ws_size) --logch;
  float* ring = (float*)(w + off);
  const int CH = 1 << logch, nch = Tq >> logch, rowTiles = CH >> 1;
  const long chrows = 64L << logch;
  const long sCz = chrows * 12800;
  const long slotStride = 2 * sCz;

  pack_l2s<<<512, 256, 0, stream>>>(l2sW, bpl2s);
  cpy_scene<<<BT, 256, 0, stream>>>(context, sceneb);
  groupsep<<<BT, 64, 0, stream>>>(feat, sepW, sepb, seqin);
  gemm_split<true><<<dim3(8, 64, 1), 256, 0, stream>>>(
      feat, 0, bpl2s, 0, sharef, 0, l2sb, 2048, 512);

  for (int l = 0; l < 2; ++l) {
    pack_layer<<<10240, 256, 0, stream>>>(Wx, Wh, Wc, bprexL, bscxL, wrecL, l);
    hipMemsetAsync(hsplit, 0, 1048576, stream);
    hipMemsetAsync(lbuf, 0, 528384, stream);
    hipMemsetAsync(cellg, 0, 262144, stream);
    hipMemsetAsync(shstat, 0, 262144, stream);
    auto pre = [&](int k) {
      long t0r = (long)(k << logch) * 64 * 512;
      gemm_split<false><<<dim3(160, rowTiles, 2), 256, 0, stream>>>(
          seqin + t0r, (long)BT * 512, bprexL, 10485760,
          ring + (size_t)(k & 1) * slotStride, sCz, nullptr, 512, 12800);
      gemm_split<false><<<dim3(40, rowTiles, 2), 256, 0, stream>>>(
          sceneb + t0r, 0, bscxL, 2621440,
          ring + (size_t)(k & 1) * slotStride + 10240, sCz, nullptr, 512, 12800);
    };
    pre(0);
    for (int k = 0; k < nch; ++k) {
      if (k + 1 < nch) pre(k + 1);
      for (int t = k << logch; t < ((k + 1) << logch); ++t)
        step_kernel<<<256, 320, 0, stream>>>(wrecL, ring, hsplit, lbuf, sgbuf,
            cellg, shstat, sharef, shout, seqin, out, archW, archB, bx, bh, cb,
            l, t, logch);
    }
    share_fin<<<128, 256, 0, stream>>>(sgbuf, shstat, sharef, shout, out, l);
  }
  (void)in_sizes; (void)n_in; (void)out_size; (void)ws_size;
}